// Round 16
// baseline (68.275 us; speedup 1.0000x reference)
//
#include <hip/hip_runtime.h>

// Round 16 = R15 (no barriers, 128-B staging segments, act folded into C1)
// at depth-1 staging + __launch_bounds__(256,4): 40 staging VGPRs -> total
// ~110 <= 128, 4 blocks/CU = 16 waves/CU (vs 12). In the saturated-queue
// regime depth doesn't matter (R11/R14 nulls); stream count does.

#define NB      65536
#define NS      64
#define NH      10
#define TSTEPS  8
#define NTILES  8
#define LSTRIDE 328   // LDS bytes per element: 8 steps * 40 B (f16) + 8 pad

typedef __fp16 f16x2 __attribute__((ext_vector_type(2)));
typedef __fp16 half8 __attribute__((ext_vector_type(8)));
typedef float  f32x4 __attribute__((ext_vector_type(4)));

#define MFMA32(a,b,c) __builtin_amdgcn_mfma_f32_16x16x32_f16((a),(b),(c),0,0,0)

__device__ __forceinline__ float ftanh(float x) {
    float e = __builtin_amdgcn_exp2f(x * 2.885390081777927f);  // 2*log2(e)
    float r = __builtin_amdgcn_rcpf(1.0f + e);
    return fmaf(-2.0f, r, 1.0f);
}
__device__ __forceinline__ f16x2 pk(float a, float b) {
    return __builtin_amdgcn_cvt_pkrtz(a, b);
}
__device__ __forceinline__ float f2f(f16x2 v) { return __builtin_bit_cast(float, v); }
__device__ __forceinline__ f16x2 bcf(float v) { return __builtin_bit_cast(f16x2, v); }

union U8 { f16x2 w[4]; half8 v; };

__global__ __launch_bounds__(256, 4)
void rd_fwd(const float* __restrict__ states, const float* __restrict__ actions,
            const float* __restrict__ W1, const float* __restrict__ b1,
            const float* __restrict__ W2, const float* __restrict__ b2,
            const float* __restrict__ W3, const float* __restrict__ b3,
            const float* __restrict__ Wg1, const float* __restrict__ bg1,
            const float* __restrict__ Wg2, const float* __restrict__ bg2,
            float* __restrict__ out)
{
    __shared__ unsigned char lds[64 * LSTRIDE];   // 20,992 B

    const int tid  = threadIdx.x;
    const int lane = tid & 63;
    const int w    = tid >> 6;                 // wave in block
    const int wg   = blockIdx.x * 4 + w;       // global wave id
    const int e    = lane & 15;                // element (B/D column)
    const int g    = lane >> 4;                // k/row group
    const int E    = wg * 16 + e;              // global element
    const int n    = e;                        // A row (neuron)
    const bool nv  = (n < NH);
    const f16x2 z  = pk(0.0f, 0.0f);

    // ---- A1 = W1^T (16x32), stacked-K: j<4 -> k=4g+j ; j>=4 -> 16+4g+(j-4)
    U8 A1;
#pragma unroll
    for (int v = 0; v < 4; ++v) {
        const int k0 = (v < 2) ? (4 * g + 2 * v) : (16 + 4 * g + 2 * (v - 2));
        A1.w[v] = pk(nv ? W1[k0 * NH + n] : 0.0f,
                     nv ? W1[(k0 + 1) * NH + n] : 0.0f);
    }
    // ---- A2/A3: valid k<10 in low K-block ----
    U8 A2, A3;
#pragma unroll
    for (int v = 0; v < 4; ++v) {
        if (v < 2) {
            const int k0 = 4 * g + 2 * v;
            const bool v0 = nv && (k0 < NH), v1 = nv && (k0 + 1 < NH);
            A2.w[v] = pk(v0 ? W2[k0 * NH + n] : 0.0f, v1 ? W2[(k0 + 1) * NH + n] : 0.0f);
            A3.w[v] = pk(v0 ? W3[k0 * NH + n] : 0.0f, v1 ? W3[(k0 + 1) * NH + n] : 0.0f);
        } else { A2.w[v] = z; A3.w[v] = z; }
    }
    // ---- C operands (row nr = 4g+r); action folded into C1 (f32) ----
    const float2 av = *(const float2*)(actions + 2 * E);
    f32x4 C1f, C2b, b3v;
#pragma unroll
    for (int r = 0; r < 4; ++r) {
        const int nr = 4 * g + r;
        const bool ok = (nr < NH);
        C1f[r] = ok ? fmaf(av.x, W1[30 * NH + nr],
                  fmaf(av.y, W1[31 * NH + nr], b1[nr])) : 0.0f;
        C2b[r] = ok ? b2[nr] : 0.0f;
        b3v[r] = ok ? b3[nr] : 0.0f;
    }

    // ---- staging: 8 lanes per element -> 128-B aligned segments (wave-local)
    const int le  = lane >> 3;                 // element-in-half (0..7)
    const int sq8 = lane & 7;                  // 16-B slot within 128-B seg
    const char* gsrc = (const char*)states
                     + (size_t)(wg * 16 + le) * 5120 + sq8 * 16;
    unsigned char* lw = &lds[(w * 16 + le) * LSTRIDE + sq8 * 8];
    const int HSTEP_G = 8 * 5120;              // half-offset, global
    const int HSTEP_L = 8 * LSTRIDE;           // half-offset, LDS

    // ---- LDS read bases (f16 byte offsets, same wave's slice) ----
    const unsigned char* lr = &lds[(w * 16 + e) * LSTRIDE];
    const int r0 = (g == 0) ? 12 : (g == 1) ? 20 : (g == 2) ? 0  : 4;
    const int r1 = (g == 0) ? 16 : (g == 1) ? 24 : (g == 2) ? 28 : 8;
    const int r2 = (g == 0) ? 16 : (g == 1) ? 24 : (g == 2) ? 32 : 36;

    // ---- prologue: issue tile 0 (depth-1: single 40-reg batch) ----
    float4 F[10];
#pragma unroll
    for (int h = 0; h < 2; ++h)
#pragma unroll
        for (int i = 0; i < 5; ++i)
            F[h * 5 + i] = *(const float4*)(gsrc + h * HSTEP_G + i * 128);

    f32x4 st = {0.0f, 0.0f, 0.0f, 0.0f};
    float u0f = f2f(z), u1f = f2f(z);

#pragma unroll 1
    for (int t = 0; t < NTILES; ++t) {
        // write tile t to LDS (vmcnt drain on the batch; wave-private slice,
        // anti-dep on previous tile's LDS reads is per-wave program order)
#pragma unroll
        for (int h = 0; h < 2; ++h)
#pragma unroll
            for (int i = 0; i < 5; ++i) {
                const float4 f = F[h * 5 + i];
                uint2 pw;
                pw.x = __builtin_bit_cast(unsigned int, pk(f.x, f.y));
                pw.y = __builtin_bit_cast(unsigned int, pk(f.z, f.w));
                *(uint2*)(lw + h * HSTEP_L + i * 64) = pw;
            }
        // re-issue the batch for tile t+1 (lands during this tile's compute)
        if (t < NTILES - 1) {
#pragma unroll
            for (int h = 0; h < 2; ++h)
#pragma unroll
                for (int i = 0; i < 5; ++i)
                    F[h * 5 + i] = *(const float4*)(gsrc + h * HSTEP_G
                                                    + (t + 1) * 640 + i * 128);
        }

#pragma unroll
        for (int s = 0; s < TSTEPS; ++s) {
            const int sb = s * 40;
            const f16x2 ow0 = bcf(*(const float*)(lr + sb + r0));
            const f16x2 ow1 = bcf(*(const float*)(lr + sb + r1));
            const f16x2 ow2 = bcf(*(const float*)(lr + sb + r2));

            // ---- B1: x = [st(0..9), obs(10..29), 0,0] (act in C1) ----
            const f16x2 u0 = bcf(u0f), u1 = bcf(u1f);
            U8 B1;
            B1.w[0] = (g == 3) ? ow0 : u0;
            B1.w[1] = (g <= 1) ? u1  : (g == 2 ? ow0 : ow1);
            B1.w[2] = (g <= 1) ? ow0 : (g == 2 ? ow1 : ow2);
            B1.w[3] = (g <= 1) ? ow1 : (g == 2 ? ow2 : z);

            // ---- layer 1 ----
            const f32x4 D1 = MFMA32(A1.v, B1.v, C1f);
            const float t0 = ftanh(D1[0]), t1 = ftanh(D1[1]),
                        t2 = ftanh(D1[2]), t3 = ftanh(D1[3]);
            U8 B2; B2.w[0] = pk(t0, t1); B2.w[1] = pk(t2, t3);
            B2.w[2] = z; B2.w[3] = z;

            // ---- layer 2 ----
            const f32x4 D2 = MFMA32(A2.v, B2.v, C2b);
            const float q0 = ftanh(D2[0]), q1 = ftanh(D2[1]),
                        q2 = ftanh(D2[2]), q3 = ftanh(D2[3]);
            U8 B3; B3.w[0] = pk(q0, q1); B3.w[1] = pk(q2, q3);
            B3.w[2] = z; B3.w[3] = z;

            // ---- layer 3: st' = W3^T h2 + (st + b3) ----
            f32x4 C3;
            C3[0] = st[0] + b3v[0]; C3[1] = st[1] + b3v[1];
            C3[2] = st[2] + b3v[2]; C3[3] = st[3] + b3v[3];
            st = MFMA32(A3.v, B3.v, C3);

            u0f = f2f(pk(st[0], st[1]));
            u1f = f2f(pk(st[2], st[3]));
        }
    }

    // ---- head (weights loaded only now) ----
    U8 Ah;
#pragma unroll
    for (int v = 0; v < 4; ++v) {
        if (v < 2) {
            const int k0 = 4 * g + 2 * v;
            const bool v0 = nv && (k0 < NH), v1 = nv && (k0 + 1 < NH);
            Ah.w[v] = pk(v0 ? Wg1[k0 * NH + n] : 0.0f, v1 ? Wg1[(k0 + 1) * NH + n] : 0.0f);
        } else Ah.w[v] = z;
    }
    f32x4 Chb;
    float wg2b[4];
#pragma unroll
    for (int r = 0; r < 4; ++r) {
        const int nr = 4 * g + r;
        Chb[r]  = (nr < NH) ? bg1[nr] : 0.0f;
        wg2b[r] = (nr < NH) ? Wg2[nr] : 0.0f;
    }
    U8 Bh; Bh.w[0] = bcf(u0f); Bh.w[1] = bcf(u1f); Bh.w[2] = z; Bh.w[3] = z;
    const f32x4 Dh = MFMA32(Ah.v, Bh.v, Chb);
    float part = 0.0f;
#pragma unroll
    for (int r = 0; r < 4; ++r) part = fmaf(ftanh(Dh[r]), wg2b[r], part);
    part += __shfl_xor(part, 16);
    part += __shfl_xor(part, 32);
    if (lane < 16) out[wg * 16 + lane] = part + bg2[0];
}

extern "C" void kernel_launch(void* const* d_in, const int* in_sizes, int n_in,
                              void* d_out, int out_size, void* d_ws, size_t ws_size,
                              hipStream_t stream) {
    const float* states  = (const float*)d_in[0];
    const float* actions = (const float*)d_in[1];
    const float* W1  = (const float*)d_in[2];
    const float* b1  = (const float*)d_in[3];
    const float* W2  = (const float*)d_in[4];
    const float* b2  = (const float*)d_in[5];
    const float* W3  = (const float*)d_in[6];
    const float* b3  = (const float*)d_in[7];
    const float* Wg1 = (const float*)d_in[8];
    const float* bg1 = (const float*)d_in[9];
    const float* Wg2 = (const float*)d_in[10];
    const float* bg2 = (const float*)d_in[11];
    float* out = (float*)d_out;

    // 65536 elements / 16 per wave / 4 waves per block = 1024 blocks
    rd_fwd<<<1024, 256, 0, stream>>>(states, actions, W1, b1, W2, b2,
                                     W3, b3, Wg1, bg1, Wg2, bg2, out);
}

// Round 18
// 67.023 us; speedup vs baseline: 1.0187x; 1.0187x over previous
//
#include <hip/hip_runtime.h>

// Round 18 = Round 17 with the compile fix: nontemporal loads go through the
// clang ext-vector f32x4 type (builtin rejects HIP_vector_type pointers).
// Experiment unchanged: partition the 335.5-MB stream; first 225 MB normal
// loads (L3-resident set), last 105 MB nontemporal (no cache alloc) so the
// streaming tail stops evicting the resident set.

#define NB      65536
#define NS      64
#define NH      10
#define TSTEPS  8
#define NTILES  8
#define LSTRIDE 328    // LDS bytes per element: 8 steps * 40 B (f16) + 8 pad
#define NTSPLIT 2816   // waves [0,2816): normal (225 MB); [2816,4096): nt

typedef __fp16 f16x2 __attribute__((ext_vector_type(2)));
typedef __fp16 half8 __attribute__((ext_vector_type(8)));
typedef float  f32x4 __attribute__((ext_vector_type(4)));

#define MFMA32(a,b,c) __builtin_amdgcn_mfma_f32_16x16x32_f16((a),(b),(c),0,0,0)

__device__ __forceinline__ float ftanh(float x) {
    float e = __builtin_amdgcn_exp2f(x * 2.885390081777927f);  // 2*log2(e)
    float r = __builtin_amdgcn_rcpf(1.0f + e);
    return fmaf(-2.0f, r, 1.0f);
}
__device__ __forceinline__ f16x2 pk(float a, float b) {
    return __builtin_amdgcn_cvt_pkrtz(a, b);
}
__device__ __forceinline__ float f2f(f16x2 v) { return __builtin_bit_cast(float, v); }
__device__ __forceinline__ f16x2 bcf(float v) { return __builtin_bit_cast(f16x2, v); }

union U8 { f16x2 w[4]; half8 v; };

__global__ __launch_bounds__(256, 3)
void rd_fwd(const float* __restrict__ states, const float* __restrict__ actions,
            const float* __restrict__ W1, const float* __restrict__ b1,
            const float* __restrict__ W2, const float* __restrict__ b2,
            const float* __restrict__ W3, const float* __restrict__ b3,
            const float* __restrict__ Wg1, const float* __restrict__ bg1,
            const float* __restrict__ Wg2, const float* __restrict__ bg2,
            float* __restrict__ out)
{
    __shared__ unsigned char lds[64 * LSTRIDE];   // 20,992 B

    const int tid  = threadIdx.x;
    const int lane = tid & 63;
    const int w    = tid >> 6;                 // wave in block
    const int wg   = blockIdx.x * 4 + w;       // global wave id
    const int e    = lane & 15;                // element (B/D column)
    const int g    = lane >> 4;                // k/row group
    const int E    = wg * 16 + e;              // global element
    const int n    = e;                        // A row (neuron)
    const bool nv  = (n < NH);
    const bool ntw = (wg >= NTSPLIT);          // streaming partition
    const f16x2 z  = pk(0.0f, 0.0f);

    // ---- A1 = W1^T (16x32), stacked-K: j<4 -> k=4g+j ; j>=4 -> 16+4g+(j-4)
    U8 A1;
#pragma unroll
    for (int v = 0; v < 4; ++v) {
        const int k0 = (v < 2) ? (4 * g + 2 * v) : (16 + 4 * g + 2 * (v - 2));
        A1.w[v] = pk(nv ? W1[k0 * NH + n] : 0.0f,
                     nv ? W1[(k0 + 1) * NH + n] : 0.0f);
    }
    // ---- A2/A3: valid k<10 in low K-block ----
    U8 A2, A3;
#pragma unroll
    for (int v = 0; v < 4; ++v) {
        if (v < 2) {
            const int k0 = 4 * g + 2 * v;
            const bool v0 = nv && (k0 < NH), v1 = nv && (k0 + 1 < NH);
            A2.w[v] = pk(v0 ? W2[k0 * NH + n] : 0.0f, v1 ? W2[(k0 + 1) * NH + n] : 0.0f);
            A3.w[v] = pk(v0 ? W3[k0 * NH + n] : 0.0f, v1 ? W3[(k0 + 1) * NH + n] : 0.0f);
        } else { A2.w[v] = z; A3.w[v] = z; }
    }
    // ---- C operands (row nr = 4g+r); action folded into C1 (f32) ----
    const float2 av = *(const float2*)(actions + 2 * E);
    f32x4 C1f, C2b, b3v;
#pragma unroll
    for (int r = 0; r < 4; ++r) {
        const int nr = 4 * g + r;
        const bool ok = (nr < NH);
        C1f[r] = ok ? fmaf(av.x, W1[30 * NH + nr],
                  fmaf(av.y, W1[31 * NH + nr], b1[nr])) : 0.0f;
        C2b[r] = ok ? b2[nr] : 0.0f;
        b3v[r] = ok ? b3[nr] : 0.0f;
    }

    // ---- staging: 8 lanes per element -> 128-B aligned segments (wave-local)
    const int le  = lane >> 3;                 // element-in-half (0..7)
    const int sq8 = lane & 7;                  // 16-B slot within 128-B seg
    const char* gsrc = (const char*)states
                     + (size_t)(wg * 16 + le) * 5120 + sq8 * 16;
    unsigned char* lw = &lds[(w * 16 + le) * LSTRIDE + sq8 * 8];
    const int HSTEP_G = 8 * 5120;              // half-offset, global
    const int HSTEP_L = 8 * LSTRIDE;           // half-offset, LDS

    // ---- LDS read bases (f16 byte offsets, same wave's slice) ----
    const unsigned char* lr = &lds[(w * 16 + e) * LSTRIDE];
    const int r0 = (g == 0) ? 12 : (g == 1) ? 20 : (g == 2) ? 0  : 4;
    const int r1 = (g == 0) ? 16 : (g == 1) ? 24 : (g == 2) ? 28 : 8;
    const int r2 = (g == 0) ? 16 : (g == 1) ? 24 : (g == 2) ? 32 : 36;

    // ---- prologue: issue tiles 0 and 1 ----
    f32x4 F0[10], F1[10];
    if (ntw) {
#pragma unroll
        for (int h = 0; h < 2; ++h)
#pragma unroll
            for (int i = 0; i < 5; ++i) {
                F0[h * 5 + i] = __builtin_nontemporal_load(
                    (const f32x4*)(gsrc + h * HSTEP_G + i * 128));
                F1[h * 5 + i] = __builtin_nontemporal_load(
                    (const f32x4*)(gsrc + h * HSTEP_G + 640 + i * 128));
            }
    } else {
#pragma unroll
        for (int h = 0; h < 2; ++h)
#pragma unroll
            for (int i = 0; i < 5; ++i) {
                F0[h * 5 + i] = *(const f32x4*)(gsrc + h * HSTEP_G + i * 128);
                F1[h * 5 + i] = *(const f32x4*)(gsrc + h * HSTEP_G + 640 + i * 128);
            }
    }

    f32x4 st = {0.0f, 0.0f, 0.0f, 0.0f};
    float u0f = f2f(z), u1f = f2f(z);

#pragma unroll 2
    for (int t = 0; t < NTILES; ++t) {
        f32x4* F = (t & 1) ? F1 : F0;
        // write tile t to LDS (wave-private slice; program order = safety)
#pragma unroll
        for (int h = 0; h < 2; ++h)
#pragma unroll
            for (int i = 0; i < 5; ++i) {
                const f32x4 f = F[h * 5 + i];
                uint2 pw;
                pw.x = __builtin_bit_cast(unsigned int, pk(f[0], f[1]));
                pw.y = __builtin_bit_cast(unsigned int, pk(f[2], f[3]));
                *(uint2*)(lw + h * HSTEP_L + i * 64) = pw;
            }
        // re-issue this batch for tile t+2
        if (t < NTILES - 2) {
            if (ntw) {
#pragma unroll
                for (int h = 0; h < 2; ++h)
#pragma unroll
                    for (int i = 0; i < 5; ++i)
                        F[h * 5 + i] = __builtin_nontemporal_load(
                            (const f32x4*)(gsrc + h * HSTEP_G
                                           + (t + 2) * 640 + i * 128));
            } else {
#pragma unroll
                for (int h = 0; h < 2; ++h)
#pragma unroll
                    for (int i = 0; i < 5; ++i)
                        F[h * 5 + i] = *(const f32x4*)(gsrc + h * HSTEP_G
                                                       + (t + 2) * 640 + i * 128);
            }
        }

#pragma unroll
        for (int s = 0; s < TSTEPS; ++s) {
            const int sb = s * 40;
            const f16x2 ow0 = bcf(*(const float*)(lr + sb + r0));
            const f16x2 ow1 = bcf(*(const float*)(lr + sb + r1));
            const f16x2 ow2 = bcf(*(const float*)(lr + sb + r2));

            // ---- B1: x = [st(0..9), obs(10..29), 0,0] (act in C1) ----
            const f16x2 u0 = bcf(u0f), u1 = bcf(u1f);
            U8 B1;
            B1.w[0] = (g == 3) ? ow0 : u0;
            B1.w[1] = (g <= 1) ? u1  : (g == 2 ? ow0 : ow1);
            B1.w[2] = (g <= 1) ? ow0 : (g == 2 ? ow1 : ow2);
            B1.w[3] = (g <= 1) ? ow1 : (g == 2 ? ow2 : z);

            // ---- layer 1 ----
            const f32x4 D1 = MFMA32(A1.v, B1.v, C1f);
            const float t0 = ftanh(D1[0]), t1 = ftanh(D1[1]),
                        t2 = ftanh(D1[2]), t3 = ftanh(D1[3]);
            U8 B2; B2.w[0] = pk(t0, t1); B2.w[1] = pk(t2, t3);
            B2.w[2] = z; B2.w[3] = z;

            // ---- layer 2 ----
            const f32x4 D2 = MFMA32(A2.v, B2.v, C2b);
            const float q0 = ftanh(D2[0]), q1 = ftanh(D2[1]),
                        q2 = ftanh(D2[2]), q3 = ftanh(D2[3]);
            U8 B3; B3.w[0] = pk(q0, q1); B3.w[1] = pk(q2, q3);
            B3.w[2] = z; B3.w[3] = z;

            // ---- layer 3: st' = W3^T h2 + (st + b3) ----
            f32x4 C3;
            C3[0] = st[0] + b3v[0]; C3[1] = st[1] + b3v[1];
            C3[2] = st[2] + b3v[2]; C3[3] = st[3] + b3v[3];
            st = MFMA32(A3.v, B3.v, C3);

            u0f = f2f(pk(st[0], st[1]));
            u1f = f2f(pk(st[2], st[3]));
        }
    }

    // ---- head (weights loaded only now) ----
    U8 Ah;
#pragma unroll
    for (int v = 0; v < 4; ++v) {
        if (v < 2) {
            const int k0 = 4 * g + 2 * v;
            const bool v0 = nv && (k0 < NH), v1 = nv && (k0 + 1 < NH);
            Ah.w[v] = pk(v0 ? Wg1[k0 * NH + n] : 0.0f, v1 ? Wg1[(k0 + 1) * NH + n] : 0.0f);
        } else Ah.w[v] = z;
    }
    f32x4 Chb;
    float wg2b[4];
#pragma unroll
    for (int r = 0; r < 4; ++r) {
        const int nr = 4 * g + r;
        Chb[r]  = (nr < NH) ? bg1[nr] : 0.0f;
        wg2b[r] = (nr < NH) ? Wg2[nr] : 0.0f;
    }
    U8 Bh; Bh.w[0] = bcf(u0f); Bh.w[1] = bcf(u1f); Bh.w[2] = z; Bh.w[3] = z;
    const f32x4 Dh = MFMA32(Ah.v, Bh.v, Chb);
    float part = 0.0f;
#pragma unroll
    for (int r = 0; r < 4; ++r) part = fmaf(ftanh(Dh[r]), wg2b[r], part);
    part += __shfl_xor(part, 16);
    part += __shfl_xor(part, 32);
    if (lane < 16) out[wg * 16 + lane] = part + bg2[0];
}

extern "C" void kernel_launch(void* const* d_in, const int* in_sizes, int n_in,
                              void* d_out, int out_size, void* d_ws, size_t ws_size,
                              hipStream_t stream) {
    const float* states  = (const float*)d_in[0];
    const float* actions = (const float*)d_in[1];
    const float* W1  = (const float*)d_in[2];
    const float* b1  = (const float*)d_in[3];
    const float* W2  = (const float*)d_in[4];
    const float* b2  = (const float*)d_in[5];
    const float* W3  = (const float*)d_in[6];
    const float* b3  = (const float*)d_in[7];
    const float* Wg1 = (const float*)d_in[8];
    const float* bg1 = (const float*)d_in[9];
    const float* Wg2 = (const float*)d_in[10];
    const float* bg2 = (const float*)d_in[11];
    float* out = (float*)d_out;

    // 65536 elements / 16 per wave / 4 waves per block = 1024 blocks
    rd_fwd<<<1024, 256, 0, stream>>>(states, actions, W1, b1, W2, b2,
                                     W3, b3, Wg1, bg1, Wg2, bg2, out);
}